// Round 1
// baseline (138.558 us; speedup 1.0000x reference)
//
#include <hip/hip_runtime.h>

#define HID 50
#define TSTEPS 512

// One wave (64 threads) per batch element. Lane j computes h[j]:
//   - row j of W_hh lives in 50 VGPRs (loaded once)
//   - h broadcast each step via a 64-float LDS buffer (broadcast reads, conflict-free)
//   - tanh via v_exp_f32 + v_rcp_f32 (NaN-free saturating form)
__global__ __launch_bounds__(64) void rnn_fused(
    const float* __restrict__ x,      // [B, 512, 1]
    const float* __restrict__ W_ih,   // [50, 1]
    const float* __restrict__ W_hh,   // [50, 50]
    const float* __restrict__ b_ih,   // [50]
    const float* __restrict__ b_hh,   // [50]
    const float* __restrict__ W_fc,   // [1, 50]
    const float* __restrict__ b_fc,   // [1]
    float* __restrict__ out)          // [B, 1]
{
    const int b = blockIdx.x;
    const int j = threadIdx.x;        // 0..63, lanes 50..63 compute dummy row 0
    __shared__ __align__(16) float hlds[64];

    const int jj = (j < HID) ? j : 0;

    float wrow[HID];
#pragma unroll
    for (int k = 0; k < HID; ++k) wrow[k] = W_hh[jj * HID + k];
    const float wih  = W_ih[jj];
    const float btot = b_ih[jj] + b_hh[jj];   // xproj bias + recurrent bias, fused
    const float wfc  = (j < HID) ? W_fc[jj] : 0.0f;
    const float bfc  = b_fc[0];

    float hb[52];                     // broadcast copy of h (52 = 13 float4)
#pragma unroll
    for (int k = 0; k < 52; ++k) hb[k] = 0.0f;

    const float* xb = x + (size_t)b * TSTEPS;
    float xv = xb[j];                 // 64 timesteps of x, one per lane
    float hn = 0.0f;

    for (int t0 = 0; t0 < TSTEPS; t0 += 64) {
        float xv_next = 0.0f;
        if (t0 + 64 < TSTEPS) xv_next = xb[t0 + 64 + j];   // prefetch next chunk

        for (int i0 = 0; i0 < 64; i0 += 8) {
#pragma unroll
            for (int ii = 0; ii < 8; ++ii) {
                const float xt = __shfl(xv, i0 + ii);      // wave-uniform x[b][t]

                // acc = x*W_ih + (b_ih + b_hh) + sum_k h[k] * W_hh[j][k]
                float a0 = fmaf(xt, wih, btot);
                float a1 = 0.0f, a2 = 0.0f, a3 = 0.0f;
#pragma unroll
                for (int k = 0; k < 48; k += 4) {
                    a0 = fmaf(hb[k+0], wrow[k+0], a0);
                    a1 = fmaf(hb[k+1], wrow[k+1], a1);
                    a2 = fmaf(hb[k+2], wrow[k+2], a2);
                    a3 = fmaf(hb[k+3], wrow[k+3], a3);
                }
                a0 = fmaf(hb[48], wrow[48], a0);
                a1 = fmaf(hb[49], wrow[49], a1);
                const float s = (a0 + a1) + (a2 + a3);

                // tanh(s) = 1 - 2/(exp(2s)+1); exp(2s) = exp2(s * 2*log2(e))
                // saturates correctly: s->+inf => e=inf => 1; s->-inf => e=0 => -1
                const float e = __builtin_amdgcn_exp2f(s * 2.88539008177792681f);
                const float r = __builtin_amdgcn_rcpf(e + 1.0f);
                hn = fmaf(-2.0f, r, 1.0f);

                // broadcast new h through LDS
                hlds[j] = hn;
                __syncthreads();       // single wave: lgkmcnt(0) + barrier
#pragma unroll
                for (int q = 0; q < 13; ++q) {
                    const float4 v = reinterpret_cast<const float4*>(hlds)[q];
                    hb[4*q+0] = v.x; hb[4*q+1] = v.y;
                    hb[4*q+2] = v.z; hb[4*q+3] = v.w;
                }
                // read->next-write ordering is guaranteed by the data dependency:
                // next hlds[j] store needs hn which needs all hb[] FMAs.
            }
        }
        xv = xv_next;
    }

    // out[b] = sum_j h[j] * W_fc[j] + b_fc   (lanes >= 50 contribute wfc=0)
    float p = hn * wfc;
#pragma unroll
    for (int off = 32; off >= 1; off >>= 1) p += __shfl_xor(p, off);
    if (j == 0) out[b] = p + bfc;
}

extern "C" void kernel_launch(void* const* d_in, const int* in_sizes, int n_in,
                              void* d_out, int out_size, void* d_ws, size_t ws_size,
                              hipStream_t stream) {
    const float* x    = (const float*)d_in[0];
    const float* W_ih = (const float*)d_in[1];
    const float* W_hh = (const float*)d_in[2];
    const float* b_ih = (const float*)d_in[3];
    const float* b_hh = (const float*)d_in[4];
    const float* W_fc = (const float*)d_in[5];
    const float* b_fc = (const float*)d_in[6];
    float* out = (float*)d_out;

    const int B = in_sizes[0] / TSTEPS;   // 2048
    rnn_fused<<<dim3(B), dim3(64), 0, stream>>>(x, W_ih, W_hh, b_ih, b_hh, W_fc, b_fc, out);
}